// Round 15
// baseline (657.782 us; speedup 1.0000x reference)
//
#include <hip/hip_runtime.h>
#include <hip/hip_bf16.h>

// SlotAttention fused pipeline for MI355X (gfx950).
// B=64, NS=11, NK=4096, all feature dims = 128, NUM_ITER=2.
//
// Algebra: logits[m][n] = qk[m].xln[n] with qk = (LN(q)@Wq*scale)@Wk^T;
//          y[m] = sum_n p[m][n] xln[n];  upd = (y/(d+eps))@Wv -> GRU.
// Dispatch chain (big-ws, 3 dispatches): kqq(+zero+cnt-reset)
//   -> kf (LN+materialize+iter1 attn; LAST BLOCK PER BATCH runs GRU finalize
//          + iter2 qq-pack + re-zero)
//   -> kb (iter2 attn; LAST BLOCK PER BATCH runs GRU finalize -> d_out).
// Last-block protocol: flush atomics -> threadfence -> atomicAdd(cnt[b]);
// 16th block re-reads yacc/dacc with device-scope atomic loads.
// Swizzle: byte(n,cb) = n*256 + (cb ^ ((n&7)<<4) ^ (((n>>3)&3)<<5)).

#define NKEYS 4096

typedef short short8 __attribute__((ext_vector_type(8)));
typedef float f32x4 __attribute__((ext_vector_type(4)));

__device__ __forceinline__ unsigned short f2bf(float x) {
    unsigned u = __float_as_uint(x);
    u += 0x7fffu + ((u >> 16) & 1u);   // round-to-nearest-even
    return (unsigned short)(u >> 16);
}

__device__ __forceinline__ int xoff(int n, int cb) {
    return n * 256 + (cb ^ ((n & 7) << 4) ^ (((n >> 3) & 3) << 5));
}

__device__ __forceinline__ void gll16(const void* g, void* l) {
    __builtin_amdgcn_global_load_lds(
        (const __attribute__((address_space(1))) unsigned int*)g,
        (__attribute__((address_space(3))) unsigned int*)l, 16, 0, 0);
}

// DPP cross-lane add (VALU pipe). CTRL compile-time const.
template <int CTRL>
__device__ __forceinline__ float dpp_add(float v) {
    return v + __int_as_float(__builtin_amdgcn_update_dpp(
        0, __float_as_int(v), CTRL, 0xF, 0xF, true));
}
// xor-16 exchange within 32 lanes (BitMode swizzle): one DS op.
__device__ __forceinline__ float swz_x16(float v) {
    return __int_as_float(__builtin_amdgcn_ds_swizzle(__float_as_int(v), 0x401F));
}

__device__ __forceinline__ float aload(const float* p) {
    return __hip_atomic_load(p, __ATOMIC_RELAXED, __HIP_MEMORY_SCOPE_AGENT);
}

// ---- finalize for batch b (256 threads, 2 slots/pass x 6 passes) ----
// mode 1: + re-zero yacc/dacc + iter2 qq-pack into qfrag.
__device__ __forceinline__ void finalize_batch(
    int b, int tid, char* smemraw,
    const float* yacc, const float* dacc, const float* qcur,
    const float* Wv, const float* W_ir, const float* b_ir,
    const float* W_iz, const float* b_iz, const float* W_hr,
    const float* W_hz, const float* W_in, const float* b_in,
    const float* W_hn, const float* b_hn, float* qnext, int mode,
    const float* lqg, const float* lqb, const float* Wq,
    const float* Wk, char* qfrag, float* yz, float* dz) {
    float* ys = (float*)smemraw;      // [2][128]
    float* us = ys + 256;             // [2][128]
    float* qs = us + 256;             // [2][128]
    float* red = qs + 256;            // [2][4]
    int grp = tid >> 7, c = tid & 127;
#pragma unroll 1
    for (int m0 = 0; m0 < 12; m0 += 2) {
        int mm = m0 + grp;
        bool act = (mm < 11);
        float yv = 0.f, qv = 0.f;
        if (act) {
            float den = aload(&dacc[b * 16 + mm]) + 1e-8f;
            yv = aload(&yacc[(b * 16 + mm) * 128 + c]) / den;
            qv = qcur[(b * 11 + mm) * 128 + c];
        }
        ys[grp * 128 + c] = yv;
        qs[grp * 128 + c] = qv;
        __syncthreads();
        float upd = 0.f;
#pragma unroll 4
        for (int k = 0; k < 128; k++) upd += ys[grp * 128 + k] * Wv[k * 128 + c];
        us[grp * 128 + c] = upd;
        __syncthreads();
        float air = 0, aiz = 0, ain = 0, ahr = 0, ahz = 0, ahn = 0;
#pragma unroll 4
        for (int k = 0; k < 128; k++) {
            float u = us[grp * 128 + k], q = qs[grp * 128 + k];
            air += u * W_ir[k * 128 + c];
            aiz += u * W_iz[k * 128 + c];
            ain += u * W_in[k * 128 + c];
            ahr += q * W_hr[k * 128 + c];
            ahz += q * W_hz[k * 128 + c];
            ahn += q * W_hn[k * 128 + c];
        }
        float r = 1.f / (1.f + expf(-(air + b_ir[c] + ahr)));
        float z = 1.f / (1.f + expf(-(aiz + b_iz[c] + ahz)));
        float n = tanhf(ain + b_in[c] + r * (ahn + b_hn[c]));
        float qn = (1.f - z) * n + z * qs[grp * 128 + c];
        if (act) qnext[(b * 11 + mm) * 128 + c] = qn;
        __syncthreads();
        if (mode) {
            if (act) {
                yz[(b * 16 + mm) * 128 + c] = 0.f;
                if (c == 0) dz[b * 16 + mm] = 0.f;
            }
            float s = qn, ss2 = qn * qn;
#pragma unroll
            for (int mask = 1; mask < 64; mask <<= 1) {
                s += __shfl_xor(s, mask);
                ss2 += __shfl_xor(ss2, mask);
            }
            int wig = (tid >> 6) & 1;
            if ((tid & 63) == 0) { red[grp * 4 + wig * 2] = s; red[grp * 4 + wig * 2 + 1] = ss2; }
            __syncthreads();
            s = red[grp * 4] + red[grp * 4 + 2];
            ss2 = red[grp * 4 + 1] + red[grp * 4 + 3];
            float mean = s * (1.f / 128.f);
            float var = ss2 * (1.f / 128.f) - mean * mean;
            float rstd = rsqrtf(var + 1e-5f);
            ys[grp * 128 + c] = (qn - mean) * rstd * lqg[c] + lqb[c];
            __syncthreads();
            float acc = 0.f;
#pragma unroll 4
            for (int k = 0; k < 128; k++) acc += ys[grp * 128 + k] * Wq[k * 128 + c];
            us[grp * 128 + c] = acc * 0.088388347648318447f;
            __syncthreads();
            const float4* wr = (const float4*)(Wk + c * 128);
            float qk = 0.f;
#pragma unroll 8
            for (int k4 = 0; k4 < 32; k4++) {
                float4 wv = wr[k4];
                qk += us[grp * 128 + k4 * 4] * wv.x + us[grp * 128 + k4 * 4 + 1] * wv.y +
                      us[grp * 128 + k4 * 4 + 2] * wv.z + us[grp * 128 + k4 * 4 + 3] * wv.w;
            }
            if (act) {
                int kc = c >> 5, hi = (c >> 3) & 3, j = c & 7;
                *(unsigned short*)(qfrag + b * 4096 + kc * 1024 + (hi * 16 + mm) * 16 + j * 2) =
                    f2bf(qk);
            }
            __syncthreads();
        }
    }
}

// ------------- kernel QQ: qk = (LN(query)@Wq*scale)@Wk^T, packed A-frags -------------
// Also zeroes yacc/dacc slices and the last-block counters.
__global__ void kqq(const float* __restrict__ query, const float* __restrict__ g,
                    const float* __restrict__ be, const float* __restrict__ Wq,
                    const float* __restrict__ Wk, char* __restrict__ qfrag,
                    float* __restrict__ yz, float* __restrict__ dz,
                    int* __restrict__ cnt) {
    int bm = blockIdx.x;
    int b = bm / 11, m = bm - b * 11;
    int c = threadIdx.x;
    yz[(b * 16 + m) * 128 + c] = 0.f;
    if (c == 0) dz[b * 16 + m] = 0.f;
    if (m == 0) {
        if (c == 0) cnt[b] = 0;
        if (c == 1) cnt[64 + b] = 0;
    }
    __shared__ float xs[128], qs[128];
    __shared__ float red[4];
    float x = query[bm * 128 + c];
    float s = x, ss = x * x;
#pragma unroll
    for (int mask = 1; mask < 64; mask <<= 1) {
        s += __shfl_xor(s, mask);
        ss += __shfl_xor(ss, mask);
    }
    int wid = threadIdx.x >> 6;
    if ((threadIdx.x & 63) == 0) { red[wid] = s; red[2 + wid] = ss; }
    __syncthreads();
    s = red[0] + red[1]; ss = red[2] + red[3];
    float mean = s * (1.f / 128.f);
    float var = ss * (1.f / 128.f) - mean * mean;
    float rstd = rsqrtf(var + 1e-5f);
    xs[c] = (x - mean) * rstd * g[c] + be[c];
    __syncthreads();
    float acc = 0.f;
#pragma unroll 8
    for (int k = 0; k < 128; k++) acc += xs[k] * Wq[k * 128 + c];
    qs[c] = acc * 0.088388347648318447f;   // 1/sqrt(128)
    __syncthreads();
    const float4* wr = (const float4*)(Wk + c * 128);   // row c of Wk
    float qk = 0.f;
#pragma unroll 8
    for (int k4 = 0; k4 < 32; k4++) {
        float4 wv = wr[k4];
        qk += qs[k4 * 4] * wv.x + qs[k4 * 4 + 1] * wv.y +
              qs[k4 * 4 + 2] * wv.z + qs[k4 * 4 + 3] * wv.w;
    }
    // A-frag packing: lane = hi*16 + m holds qk[m][kc*32 + hi*8 + j]
    int kc = c >> 5, hi = (c >> 3) & 3, j = c & 7;
    *(unsigned short*)(qfrag + b * 4096 + kc * 1024 + (hi * 16 + m) * 16 + j * 2) = f2bf(qk);
}

// ------------- kernel F: LN + materialize xln + iter-1 attention (once) -------------
// x/p double-buffered, 2 barriers/tile, DPP LN. Last block per batch: finalize.
__global__ __launch_bounds__(256) void kf(
    const float* __restrict__ inputs, const float* __restrict__ gkv,
    const float* __restrict__ bkv, const char* __restrict__ qfragc,
    char* __restrict__ kg, float* __restrict__ yacc, float* __restrict__ dacc_g,
    int* __restrict__ cnt, const float* __restrict__ query,
    const float* __restrict__ Wv,
    const float* __restrict__ W_ir, const float* __restrict__ b_ir,
    const float* __restrict__ W_iz, const float* __restrict__ b_iz,
    const float* __restrict__ W_hr, const float* __restrict__ W_hz,
    const float* __restrict__ W_in, const float* __restrict__ b_in,
    const float* __restrict__ W_hn, const float* __restrict__ b_hn,
    float* __restrict__ query_buf, const float* __restrict__ lqg,
    const float* __restrict__ lqb, const float* __restrict__ Wq,
    const float* __restrict__ Wk, char* __restrict__ qfragw) {
    __shared__ __align__(16) char smem[36864];   // x dbuf 2x16K + p dbuf 2x2K
    __shared__ int lastf;
    const int PO = 32768;
    int tid = threadIdx.x;
    int b = blockIdx.x >> 4, gt = blockIdx.x & 15;   // 4 tiles per block
    int w = tid >> 6, lane = tid & 63, hi = lane >> 4, lo = lane & 15;
    int a_ = tid >> 5, col4 = tid & 31;

    short8 qa[4];
#pragma unroll
    for (int kc = 0; kc < 4; kc++)
        qa[kc] = *(const short8*)(qfragc + b * 4096 + kc * 1024 + lane * 16);

    float4 g4  = *(const float4*)(gkv + col4 * 4);
    float4 be4 = *(const float4*)(bkv + col4 * 4);

    f32x4 y0 = {0, 0, 0, 0}, y1 = {0, 0, 0, 0};
    float dr[4] = {0, 0, 0, 0};

    const float4* inp4 = (const float4*)(inputs + ((size_t)b * NKEYS + gt * 256) * 128);

    float4 xa[8];
#pragma unroll
    for (int i = 0; i < 8; i++) xa[i] = inp4[tid + 256 * i];

#pragma unroll
    for (int t = 0; t < 4; t++) {
        int XB = (t & 1) * 16384;
        int PB = PO + (t & 1) * 2048;
        float4 xb[8];
        if (t < 3) {
#pragma unroll
            for (int i = 0; i < 8; i++) xb[i] = inp4[(t + 1) * 2048 + tid + 256 * i];
        }
        size_t tb = ((size_t)(b * 64 + gt * 4 + t)) * 16384;
        // ---- LN -> bf16: LDS (swizzled, buf t&1) + coalesced dump to kg ----
#pragma unroll
        for (int i = 0; i < 8; i++) {
            float4 xv = xa[i];
            int row = a_ + 8 * i;
            float s = xv.x + xv.y + xv.z + xv.w;
            float ss = xv.x * xv.x + xv.y * xv.y + xv.z * xv.z + xv.w * xv.w;
            s = dpp_add<0xB1>(s);  ss = dpp_add<0xB1>(ss);
            s = dpp_add<0x4E>(s);  ss = dpp_add<0x4E>(ss);
            s = dpp_add<0x141>(s); ss = dpp_add<0x141>(ss);
            s = dpp_add<0x140>(s); ss = dpp_add<0x140>(ss);
            s += swz_x16(s);       ss += swz_x16(ss);
            float mean = s * (1.f / 128.f);
            float var = ss * (1.f / 128.f) - mean * mean;
            float rstd = rsqrtf(var + 1e-5f);
            unsigned short h0 = f2bf((xv.x - mean) * rstd * g4.x + be4.x);
            unsigned short h1 = f2bf((xv.y - mean) * rstd * g4.y + be4.y);
            unsigned short h2 = f2bf((xv.z - mean) * rstd * g4.z + be4.z);
            unsigned short h3 = f2bf((xv.w - mean) * rstd * g4.w + be4.w);
            uint2 pk;
            pk.x = (unsigned)h0 | ((unsigned)h1 << 16);
            pk.y = (unsigned)h2 | ((unsigned)h3 << 16);
            int off = xoff(row, col4 * 8);
            *(uint2*)(smem + XB + off) = pk;
            *(uint2*)(kg + tb + off) = pk;   // same image; wave covers full rows
        }
        asm volatile("s_waitcnt lgkmcnt(0)" ::: "memory");
        __builtin_amdgcn_s_barrier();                     // 1: x-tile visible
        __builtin_amdgcn_sched_barrier(0);

        // ---- logits (wave w: keys [16w,16w+16)) ----
        f32x4 lacc = {0, 0, 0, 0};
        int n = w * 16 + lo;
#pragma unroll
        for (int kc = 0; kc < 4; kc++) {
            short8 kf8 = *(short8*)(smem + XB + xoff(n, kc * 64 + hi * 16));
            lacc = __builtin_amdgcn_mfma_f32_16x16x32_bf16(qa[kc], kf8, lacc, 0, 0, 0);
        }
        // ---- softmax over slots ----
        float mx = -1e30f;
#pragma unroll
        for (int r = 0; r < 4; r++) {
            int m = hi * 4 + r;
            mx = fmaxf(mx, (m < 11) ? lacc[r] : -1e30f);
        }
        mx = fmaxf(mx, __shfl_xor(mx, 16));
        mx = fmaxf(mx, __shfl_xor(mx, 32));
        float p[4]; float s = 0.f;
#pragma unroll
        for (int r = 0; r < 4; r++) {
            int m = hi * 4 + r;
            p[r] = (m < 11) ? __expf(lacc[r] - mx) : 0.f;
            s += p[r];
        }
        s += __shfl_xor(s, 16);
        s += __shfl_xor(s, 32);
        float inv = 1.f / s;
#pragma unroll
        for (int r = 0; r < 4; r++) {
            p[r] *= inv;
            dr[r] += p[r];
            int m = hi * 4 + r;
            *(unsigned short*)(smem + PB + m * 128 + (((w * 16 + lo) * 2) ^ ((m & 7) << 4))) =
                f2bf(p[r]);
        }
        asm volatile("s_waitcnt lgkmcnt(0)" ::: "memory");
        __builtin_amdgcn_s_barrier();                     // 2: p visible
        __builtin_amdgcn_sched_barrier(0);

        // ---- PV: y += p @ xln; no 3rd barrier (other buffers next tile) ----
#pragma unroll
        for (int s2 = 0; s2 < 2; s2++) {
            short8 pf = *(short8*)(smem + PB + lo * 128 + ((s2 * 64 + hi * 16) ^ ((lo & 7) << 4)));
            short8 v0, v1;
#pragma unroll
            for (int j = 0; j < 8; j++) {
                int nn = s2 * 32 + hi * 8 + j;
                v0[j] = *(short*)(smem + XB + xoff(nn, (w * 32 + lo) * 2));
                v1[j] = *(short*)(smem + XB + xoff(nn, (w * 32 + 16 + lo) * 2));
            }
            y0 = __builtin_amdgcn_mfma_f32_16x16x32_bf16(pf, v0, y0, 0, 0, 0);
            y1 = __builtin_amdgcn_mfma_f32_16x16x32_bf16(pf, v1, y1, 0, 0, 0);
        }
        if (t < 3) {
#pragma unroll
            for (int i = 0; i < 8; i++) xa[i] = xb[i];
        }
    }

    // ---- flush partials ----
#pragma unroll
    for (int r = 0; r < 4; r++) {
        int m = hi * 4 + r;
        if (m < 11) {
            atomicAdd(&yacc[(b * 16 + m) * 128 + w * 32 + lo], y0[r]);
            atomicAdd(&yacc[(b * 16 + m) * 128 + w * 32 + 16 + lo], y1[r]);
        }
    }
#pragma unroll
    for (int mask = 1; mask < 16; mask <<= 1) {
#pragma unroll
        for (int r = 0; r < 4; r++) dr[r] += __shfl_xor(dr[r], mask);
    }
    if (lo == 0) {
#pragma unroll
        for (int r = 0; r < 4; r++) {
            int m = hi * 4 + r;
            if (m < 11) atomicAdd(&dacc_g[b * 16 + m], dr[r]);
        }
    }

    // ---- last block of batch b: GRU finalize + iter2 qq + re-zero ----
    __threadfence();
    __syncthreads();
    if (tid == 0) lastf = (atomicAdd(&cnt[b], 1) == 15);
    __syncthreads();
    if (lastf) {
        __threadfence();
        finalize_batch(b, tid, smem, yacc, dacc_g, query, Wv,
                       W_ir, b_ir, W_iz, b_iz, W_hr, W_hz, W_in, b_in,
                       W_hn, b_hn, query_buf, 1, lqg, lqb, Wq, Wk,
                       qfragw, yacc, dacc_g);
    }
}

// ------------- kernel B: iter-2 attention from materialized xln -------------
// 2 barriers/tile; stage issued after barrier A. Last block per batch: finalize.
__global__ __launch_bounds__(256) void kb(
    const char* __restrict__ kg, const char* __restrict__ qfrag,
    float* __restrict__ yacc, float* __restrict__ dacc_g,
    int* __restrict__ cnt, const float* __restrict__ query_buf,
    const float* __restrict__ Wv,
    const float* __restrict__ W_ir, const float* __restrict__ b_ir,
    const float* __restrict__ W_iz, const float* __restrict__ b_iz,
    const float* __restrict__ W_hr, const float* __restrict__ W_hz,
    const float* __restrict__ W_in, const float* __restrict__ b_in,
    const float* __restrict__ W_hn, const float* __restrict__ b_hn,
    float* __restrict__ qout) {
    __shared__ __align__(16) char smem[34816];   // x dbuf 2x16K + p 2K
    __shared__ int lastf;
    const int PO = 32768;
    int tid = threadIdx.x;
    int b = blockIdx.x >> 4, gt = blockIdx.x & 15;   // 4 tiles per block
    int w = tid >> 6, lane = tid & 63, hi = lane >> 4, lo = lane & 15;

    short8 qa[4];
#pragma unroll
    for (int kc = 0; kc < 4; kc++)
        qa[kc] = *(const short8*)(qfrag + b * 4096 + kc * 1024 + lane * 16);

    f32x4 y0 = {0, 0, 0, 0}, y1 = {0, 0, 0, 0};
    float dr[4] = {0, 0, 0, 0};

    size_t base = ((size_t)(b * 64 + gt * 4)) * 16384;
    int reg = w * 4096;   // per-wave staging region

    // prologue: stage tile 0 into buf0
#pragma unroll
    for (int j = 0; j < 4; j++) {
        int o = reg + j * 1024;
        gll16(kg + base + o + lane * 16, smem + o);
    }

#pragma unroll
    for (int t = 0; t < 4; t++) {
        int XB = (t & 1) * 16384;
        asm volatile("s_waitcnt vmcnt(0)" ::: "memory");
        __builtin_amdgcn_s_barrier();          // A
        __builtin_amdgcn_sched_barrier(0);
        if (t < 3) {
            size_t tbn = base + (size_t)(t + 1) * 16384;
            int nb = ((t + 1) & 1) * 16384;
#pragma unroll
            for (int j = 0; j < 4; j++) {
                int o = reg + j * 1024;
                gll16(kg + tbn + o + lane * 16, smem + nb + o);
            }
        }

        // ---- logits ----
        f32x4 lacc = {0, 0, 0, 0};
        int n = w * 16 + lo;
#pragma unroll
        for (int kc = 0; kc < 4; kc++) {
            short8 kf8 = *(short8*)(smem + XB + xoff(n, kc * 64 + hi * 16));
            lacc = __builtin_amdgcn_mfma_f32_16x16x32_bf16(qa[kc], kf8, lacc, 0, 0, 0);
        }
        // ---- softmax ----
        float mx = -1e30f;
#pragma unroll
        for (int r = 0; r < 4; r++) {
            int m = hi * 4 + r;
            mx = fmaxf(mx, (m < 11) ? lacc[r] : -1e30f);
        }
        mx = fmaxf(mx, __shfl_xor(mx, 16));
        mx = fmaxf(mx, __shfl_xor(mx, 32));
        float p[4]; float s = 0.f;
#pragma unroll
        for (int r = 0; r < 4; r++) {
            int m = hi * 4 + r;
            p[r] = (m < 11) ? __expf(lacc[r] - mx) : 0.f;
            s += p[r];
        }
        s += __shfl_xor(s, 16);
        s += __shfl_xor(s, 32);
        float inv = 1.f / s;
#pragma unroll
        for (int r = 0; r < 4; r++) {
            p[r] *= inv;
            dr[r] += p[r];
            int m = hi * 4 + r;
            *(unsigned short*)(smem + PO + m * 128 + (((w * 16 + lo) * 2) ^ ((m & 7) << 4))) =
                f2bf(p[r]);
        }
        asm volatile("s_waitcnt lgkmcnt(0)" ::: "memory");
        __builtin_amdgcn_s_barrier();          // B: p visible
        __builtin_amdgcn_sched_barrier(0);

        // ---- PV ----
#pragma unroll
        for (int s2 = 0; s2 < 2; s2++) {
            short8 pf = *(short8*)(smem + PO + lo * 128 + ((s2 * 64 + hi * 16) ^ ((lo & 7) << 4)));
            short8 v0, v1;
#pragma unroll
            for (int j = 0; j < 8; j++) {
                int nn = s2 * 32 + hi * 8 + j;
                v0[j] = *(short*)(smem + XB + xoff(nn, (w * 32 + lo) * 2));
                v1[j] = *(short*)(smem + XB + xoff(nn, (w * 32 + 16 + lo) * 2));
            }
            y0 = __builtin_amdgcn_mfma_f32_16x16x32_bf16(pf, v0, y0, 0, 0, 0);
            y1 = __builtin_amdgcn_mfma_f32_16x16x32_bf16(pf, v1, y1, 0, 0, 0);
        }
        asm volatile("s_waitcnt lgkmcnt(0)" ::: "memory");   // PV reads drained
        __builtin_amdgcn_sched_barrier(0);
    }

    // ---- flush partials ----
#pragma unroll
    for (int r = 0; r < 4; r++) {
        int m = hi * 4 + r;
        if (m < 11) {
            atomicAdd(&yacc[(b * 16 + m) * 128 + w * 32 + lo], y0[r]);
            atomicAdd(&yacc[(b * 16 + m) * 128 + w * 32 + 16 + lo], y1[r]);
        }
    }
#pragma unroll
    for (int mask = 1; mask < 16; mask <<= 1) {
#pragma unroll
        for (int r = 0; r < 4; r++) dr[r] += __shfl_xor(dr[r], mask);
    }
    if (lo == 0) {
#pragma unroll
        for (int r = 0; r < 4; r++) {
            int m = hi * 4 + r;
            if (m < 11) atomicAdd(&dacc_g[b * 16 + m], dr[r]);
        }
    }

    // ---- last block of batch b: GRU finalize -> d_out ----
    __threadfence();
    __syncthreads();
    if (tid == 0) lastf = (atomicAdd(&cnt[64 + b], 1) == 15);
    __syncthreads();
    if (lastf) {
        __threadfence();
        finalize_batch(b, tid, smem, yacc, dacc_g, query_buf, Wv,
                       W_ir, b_ir, W_iz, b_iz, W_hr, W_hz, W_in, b_in,
                       W_hn, b_hn, qout, 0, nullptr, nullptr, nullptr,
                       nullptr, nullptr, nullptr, nullptr);
    }
}

// ================= fallback path (round-1, proven) =================
__global__ void kq(const float* __restrict__ query, const float* __restrict__ g,
                   const float* __restrict__ be, const float* __restrict__ Wq,
                   float* __restrict__ qout) {
    int bm = blockIdx.x;
    int c = threadIdx.x;
    __shared__ float xs[128];
    __shared__ float red[4];
    float x = query[bm * 128 + c];
    float s = x, ss = x * x;
#pragma unroll
    for (int mask = 1; mask < 64; mask <<= 1) {
        s += __shfl_xor(s, mask);
        ss += __shfl_xor(ss, mask);
    }
    int wid = threadIdx.x >> 6;
    if ((threadIdx.x & 63) == 0) { red[wid] = s; red[2 + wid] = ss; }
    __syncthreads();
    s = red[0] + red[1]; ss = red[2] + red[3];
    float mean = s * (1.f / 128.f);
    float var = ss * (1.f / 128.f) - mean * mean;
    float rstd = rsqrtf(var + 1e-5f);
    xs[c] = (x - mean) * rstd * g[c] + be[c];
    __syncthreads();
    float acc = 0.f;
#pragma unroll 8
    for (int k = 0; k < 128; k++) acc += xs[k] * Wq[k * 128 + c];
    qout[bm * 128 + c] = acc * 0.088388347648318447f;
}

__global__ __launch_bounds__(256) void ks(
    const float* __restrict__ inputs, const float* __restrict__ gkv,
    const float* __restrict__ bkv, const float* __restrict__ Wk,
    const float* __restrict__ Wv, const float* __restrict__ qbuf,
    float* __restrict__ upd_acc, float* __restrict__ d_acc) {
    __shared__ __align__(16) char smem[51200];
    const int XO = 0, KO = 16384, VB = 32768, PO = 49152;

    int tid = threadIdx.x;
    int b = blockIdx.x >> 4, g = blockIdx.x & 15;
    int w = tid >> 6, lane = tid & 63, hi = lane >> 4, lo = lane & 15;

    short8 bk[2][4], bv[2][4];
#pragma unroll
    for (int ct = 0; ct < 2; ct++) {
        int col = w * 32 + ct * 16 + lo;
#pragma unroll
        for (int kc = 0; kc < 4; kc++) {
            short8 fk, fv;
#pragma unroll
            for (int j = 0; j < 8; j++) {
                int rr = kc * 32 + hi * 8 + j;
                fk[j] = (short)f2bf(Wk[rr * 128 + col]);
                fv[j] = (short)f2bf(Wv[rr * 128 + col]);
            }
            bk[ct][kc] = fk; bv[ct][kc] = fv;
        }
    }
    short8 qa[4];
#pragma unroll
    for (int kc = 0; kc < 4; kc++) {
        short8 f;
#pragma unroll
        for (int j = 0; j < 8; j++)
            f[j] = (lo < 11) ? (short)f2bf(qbuf[(b * 11 + lo) * 128 + kc * 32 + hi * 8 + j])
                             : (short)0;
        qa[kc] = f;
    }
    int col4 = tid & 31;
    float4 g4  = *(const float4*)(gkv + col4 * 4);
    float4 be4 = *(const float4*)(bkv + col4 * 4);

    f32x4 uacc0 = {0, 0, 0, 0}, uacc1 = {0, 0, 0, 0};
    float dacc[4] = {0, 0, 0, 0};

    const float4* inp4 = (const float4*)(inputs + ((size_t)b * NKEYS + g * 256) * 128);
    int a_ = tid >> 5;

    for (int t = 0; t < 4; t++) {
#pragma unroll
        for (int i = 0; i < 8; i++) {
            int f = tid + 256 * i;
            float4 xv = inp4[t * 2048 + f];
            int row = a_ + 8 * i;
            float s = xv.x + xv.y + xv.z + xv.w;
            float ss = xv.x * xv.x + xv.y * xv.y + xv.z * xv.z + xv.w * xv.w;
#pragma unroll
            for (int mask = 1; mask < 32; mask <<= 1) {
                s += __shfl_xor(s, mask);
                ss += __shfl_xor(ss, mask);
            }
            float mean = s * (1.f / 128.f);
            float var = ss * (1.f / 128.f) - mean * mean;
            float rstd = rsqrtf(var + 1e-5f);
            unsigned short h0 = f2bf((xv.x - mean) * rstd * g4.x + be4.x);
            unsigned short h1 = f2bf((xv.y - mean) * rstd * g4.y + be4.y);
            unsigned short h2 = f2bf((xv.z - mean) * rstd * g4.z + be4.z);
            unsigned short h3 = f2bf((xv.w - mean) * rstd * g4.w + be4.w);
            uint2 pk;
            pk.x = (unsigned)h0 | ((unsigned)h1 << 16);
            pk.y = (unsigned)h2 | ((unsigned)h3 << 16);
            int byte = row * 256 + ((col4 * 8) ^ ((row & 7) << 4));
            *(uint2*)(smem + XO + byte) = pk;
        }
        __syncthreads();
#pragma unroll
        for (int mt = 0; mt < 4; mt++) {
            f32x4 ka0 = {0,0,0,0}, ka1 = {0,0,0,0}, va0 = {0,0,0,0}, va1 = {0,0,0,0};
            int arow = mt * 16 + lo;
#pragma unroll
            for (int kc = 0; kc < 4; kc++) {
                int abyte = arow * 256 + ((kc * 64 + hi * 16) ^ ((arow & 7) << 4));
                short8 af = *(short8*)(smem + XO + abyte);
                ka0 = __builtin_amdgcn_mfma_f32_16x16x32_bf16(af, bk[0][kc], ka0, 0, 0, 0);
                ka1 = __builtin_amdgcn_mfma_f32_16x16x32_bf16(af, bk[1][kc], ka1, 0, 0, 0);
                va0 = __builtin_amdgcn_mfma_f32_16x16x32_bf16(af, bv[0][kc], va0, 0, 0, 0);
                va1 = __builtin_amdgcn_mfma_f32_16x16x32_bf16(af, bv[1][kc], va1, 0, 0, 0);
            }
#pragma unroll
            for (int r = 0; r < 4; r++) {
                int n = mt * 16 + hi * 4 + r;
                int c0 = w * 32 + lo;
                int c1 = c0 + 16;
                *(unsigned short*)(smem + KO + n * 256 + ((c0 * 2) ^ ((n & 7) << 4))) = f2bf(ka0[r]);
                *(unsigned short*)(smem + KO + n * 256 + ((c1 * 2) ^ ((n & 7) << 4))) = f2bf(ka1[r]);
                *(unsigned short*)(smem + VB + c0 * 128 + ((n * 2) ^ ((c0 & 7) << 4))) = f2bf(va0[r]);
                *(unsigned short*)(smem + VB + c1 * 128 + ((n * 2) ^ ((c1 & 7) << 4))) = f2bf(va1[r]);
            }
        }
        __syncthreads();
        {
            f32x4 lacc = {0, 0, 0, 0};
            int n = w * 16 + lo;
#pragma unroll
            for (int kc = 0; kc < 4; kc++) {
                int kbyte = n * 256 + ((kc * 64 + hi * 16) ^ ((n & 7) << 4));
                short8 kf8 = *(short8*)(smem + KO + kbyte);
                lacc = __builtin_amdgcn_mfma_f32_16x16x32_bf16(qa[kc], kf8, lacc, 0, 0, 0);
            }
            float mx = -1e30f;
#pragma unroll
            for (int r = 0; r < 4; r++) {
                int m = hi * 4 + r;
                float v = (m < 11) ? lacc[r] : -1e30f;
                mx = fmaxf(mx, v);
            }
            mx = fmaxf(mx, __shfl_xor(mx, 16));
            mx = fmaxf(mx, __shfl_xor(mx, 32));
            float p[4]; float s = 0.f;
#pragma unroll
            for (int r = 0; r < 4; r++) {
                int m = hi * 4 + r;
                p[r] = (m < 11) ? __expf(lacc[r] - mx) : 0.f;
                s += p[r];
            }
            s += __shfl_xor(s, 16);
            s += __shfl_xor(s, 32);
            float inv = 1.f / s;
#pragma unroll
            for (int r = 0; r < 4; r++) {
                p[r] *= inv;
                dacc[r] += p[r];
                int m = hi * 4 + r;
                *(unsigned short*)(smem + PO + m * 128 + (((w * 16 + lo) * 2) ^ ((m & 7) << 4))) =
                    f2bf(p[r]);
            }
        }
        __syncthreads();
#pragma unroll
        for (int kc2 = 0; kc2 < 2; kc2++) {
            int pbyte = lo * 128 + ((kc2 * 64 + hi * 16) ^ ((lo & 7) << 4));
            short8 pf = *(short8*)(smem + PO + pbyte);
            int c0 = w * 32 + lo;
            int vb0 = c0 * 128 + ((kc2 * 64 + hi * 16) ^ ((c0 & 7) << 4));
            short8 vf0 = *(short8*)(smem + VB + vb0);
            uacc0 = __builtin_amdgcn_mfma_f32_16x16x32_bf16(pf, vf0, uacc0, 0, 0, 0);
            int c1 = c0 + 16;
            int vb1 = c1 * 128 + ((kc2 * 64 + hi * 16) ^ ((c1 & 7) << 4));
            short8 vf1 = *(short8*)(smem + VB + vb1);
            uacc1 = __builtin_amdgcn_mfma_f32_16x16x32_bf16(pf, vf1, uacc1, 0, 0, 0);
        }
    }
#pragma unroll
    for (int r = 0; r < 4; r++) {
        int m = hi * 4 + r;
        if (m < 11) {
            atomicAdd(&upd_acc[(b * 16 + m) * 128 + w * 32 + lo], uacc0[r]);
            atomicAdd(&upd_acc[(b * 16 + m) * 128 + w * 32 + 16 + lo], uacc1[r]);
        }
    }
#pragma unroll
    for (int mask = 1; mask < 16; mask <<= 1) {
#pragma unroll
        for (int r = 0; r < 4; r++) dacc[r] += __shfl_xor(dacc[r], mask);
    }
    if (lo == 0) {
#pragma unroll
        for (int r = 0; r < 4; r++) {
            int m = hi * 4 + r;
            if (m < 11) atomicAdd(&d_acc[b * 16 + m], dacc[r]);
        }
    }
}

__global__ void ku(const float* __restrict__ upd_acc, const float* __restrict__ d_acc,
                   const float* __restrict__ qcur,
                   const float* __restrict__ W_ir, const float* __restrict__ b_ir,
                   const float* __restrict__ W_iz, const float* __restrict__ b_iz,
                   const float* __restrict__ W_hr, const float* __restrict__ W_hz,
                   const float* __restrict__ W_in, const float* __restrict__ b_in,
                   const float* __restrict__ W_hn, const float* __restrict__ b_hn,
                   float* __restrict__ qnext) {
    int bm = blockIdx.x;
    int b = bm / 11, m = bm % 11;
    int c = threadIdx.x;
    __shared__ float us[128], qs[128];
    float den = d_acc[b * 16 + m] + 1e-8f;
    us[c] = upd_acc[(b * 16 + m) * 128 + c] / den;
    qs[c] = qcur[bm * 128 + c];
    __syncthreads();
    float air = 0, aiz = 0, ain = 0, ahr = 0, ahz = 0, ahn = 0;
#pragma unroll 4
    for (int k = 0; k < 128; k++) {
        float u = us[k], q = qs[k];
        air += u * W_ir[k * 128 + c];
        aiz += u * W_iz[k * 128 + c];
        ain += u * W_in[k * 128 + c];
        ahr += q * W_hr[k * 128 + c];
        ahz += q * W_hz[k * 128 + c];
        ahn += q * W_hn[k * 128 + c];
    }
    float r = 1.f / (1.f + expf(-(air + b_ir[c] + ahr)));
    float z = 1.f / (1.f + expf(-(aiz + b_iz[c] + ahz)));
    float n = tanhf(ain + b_in[c] + r * (ahn + b_hn[c]));
    qnext[bm * 128 + c] = (1.f - z) * n + z * qs[c];
}

// ---------------- launch ----------------
extern "C" void kernel_launch(void* const* d_in, const int* in_sizes, int n_in,
                              void* d_out, int out_size, void* d_ws, size_t ws_size,
                              hipStream_t stream) {
    const float* query   = (const float*)d_in[0];
    const float* inputs  = (const float*)d_in[1];
    const float* ln_q_g  = (const float*)d_in[2];
    const float* ln_q_b  = (const float*)d_in[3];
    const float* ln_kv_g = (const float*)d_in[4];
    const float* ln_kv_b = (const float*)d_in[5];
    const float* Wq      = (const float*)d_in[6];
    const float* Wk      = (const float*)d_in[7];
    const float* Wv      = (const float*)d_in[8];
    const float* W_ir    = (const float*)d_in[9];
    const float* b_ir    = (const float*)d_in[10];
    const float* W_iz    = (const float*)d_in[11];
    const float* b_iz    = (const float*)d_in[12];
    const float* W_hr    = (const float*)d_in[13];
    const float* W_hz    = (const float*)d_in[14];
    const float* W_in    = (const float*)d_in[15];
    const float* b_in    = (const float*)d_in[16];
    const float* W_hn    = (const float*)d_in[17];
    const float* b_hn    = (const float*)d_in[18];

    char* ws = (char*)d_ws;
    float* query_buf = (float*)(ws);             // 64*11*128 f32 = 360448 B
    float* yacc      = (float*)(ws + 360448);    // 64*16*128 f32 = 524288 B
    float* dacc      = (float*)(ws + 884736);    // 64*16 f32     = 4096 B
    char*  qfrag     = ws + 888832;              // 64*4*64*16    = 262144 B
    int*   cnt       = (int*)(ws + 1150976);     // 128 ints      = 512 B
    char*  kg        = ws + 1155072;             // 4096 tiles * 16KB = 64 MB
    const size_t need = 1155072ull + 67108864ull;

    if (ws_size >= need) {
        // 3 dispatches: kqq -> kf(+finalize1) -> kb(+finalize2)
        kqq<<<704, 128, 0, stream>>>(query, ln_q_g, ln_q_b, Wq, Wk, qfrag,
                                     yacc, dacc, cnt);
        kf<<<1024, 256, 0, stream>>>(inputs, ln_kv_g, ln_kv_b, qfrag, kg, yacc, dacc,
                                     cnt, query, Wv, W_ir, b_ir, W_iz, b_iz,
                                     W_hr, W_hz, W_in, b_in, W_hn, b_hn,
                                     query_buf, ln_q_g, ln_q_b, Wq, Wk, qfrag);
        kb<<<1024, 256, 0, stream>>>(kg, qfrag, yacc, dacc, cnt, query_buf, Wv,
                                     W_ir, b_ir, W_iz, b_iz, W_hr, W_hz,
                                     W_in, b_in, W_hn, b_hn, (float*)d_out);
    } else {
        float* q_buf = (float*)(ws + 888832);
        const float* cur = query;
        for (int it = 0; it < 2; it++) {
            kq<<<704, 128, 0, stream>>>(cur, ln_q_g, ln_q_b, Wq, q_buf);
            hipMemsetAsync(ws + 360448, 0, 524288 + 4096, stream);
            ks<<<1024, 256, 0, stream>>>(inputs, ln_kv_g, ln_kv_b, Wk, Wv, q_buf, yacc, dacc);
            float* qn = (it == 0) ? query_buf : (float*)d_out;
            ku<<<704, 128, 0, stream>>>(yacc, dacc, cur,
                                        W_ir, b_ir, W_iz, b_iz, W_hr, W_hz,
                                        W_in, b_in, W_hn, b_hn, qn);
            cur = query_buf;
        }
    }
}

// Round 16
// 142.106 us; speedup vs baseline: 4.6288x; 4.6288x over previous
//
#include <hip/hip_runtime.h>
#include <hip/hip_bf16.h>

// SlotAttention fused pipeline for MI355X (gfx950).
// B=64, NS=11, NK=4096, all feature dims = 128, NUM_ITER=2.
//
// Algebra: logits[m][n] = qk[m].xln[n] with qk = (LN(q)@Wq*scale)@Wk^T;
//          y[m] = sum_n p[m][n] xln[n];  upd = (y/(d+eps))@Wv -> GRU.
// Dispatch chain (big-ws): kqq(+zero) -> kf (LN+materialize+iter1 attn)
//   -> kun1 (GRU + fused qq + re-zero) -> kb (iter2 attn) -> kun2.
// kf: x/p double-buffered, 2 barriers/tile, DPP LN reduce (round-11 proven).
// kb: x double-buffered, 2 barriers/tile, stage after barrier A (round-11).
// Round-15 lesson: per-block __threadfence() last-block fusion = 4.6x slowdown
// (device-scope fence x1024 blocks serializes L2). Reverted to 5-dispatch chain.
// Swizzle: byte(n,cb) = n*256 + (cb ^ ((n&7)<<4) ^ (((n>>3)&3)<<5)).

#define NKEYS 4096

typedef short short8 __attribute__((ext_vector_type(8)));
typedef float f32x4 __attribute__((ext_vector_type(4)));

__device__ __forceinline__ unsigned short f2bf(float x) {
    unsigned u = __float_as_uint(x);
    u += 0x7fffu + ((u >> 16) & 1u);   // round-to-nearest-even
    return (unsigned short)(u >> 16);
}

__device__ __forceinline__ int xoff(int n, int cb) {
    return n * 256 + (cb ^ ((n & 7) << 4) ^ (((n >> 3) & 3) << 5));
}

__device__ __forceinline__ void gll16(const void* g, void* l) {
    __builtin_amdgcn_global_load_lds(
        (const __attribute__((address_space(1))) unsigned int*)g,
        (__attribute__((address_space(3))) unsigned int*)l, 16, 0, 0);
}

// DPP cross-lane add (VALU pipe). CTRL compile-time const.
template <int CTRL>
__device__ __forceinline__ float dpp_add(float v) {
    return v + __int_as_float(__builtin_amdgcn_update_dpp(
        0, __float_as_int(v), CTRL, 0xF, 0xF, true));
}
// xor-16 exchange within 32 lanes (BitMode swizzle): one DS op.
__device__ __forceinline__ float swz_x16(float v) {
    return __int_as_float(__builtin_amdgcn_ds_swizzle(__float_as_int(v), 0x401F));
}

// ------------- kernel QQ: qk = (LN(query)@Wq*scale)@Wk^T, packed A-frags -------------
// Also zeroes this block's yacc/dacc slice (replaces memset dispatch).
__global__ void kqq(const float* __restrict__ query, const float* __restrict__ g,
                    const float* __restrict__ be, const float* __restrict__ Wq,
                    const float* __restrict__ Wk, char* __restrict__ qfrag,
                    float* __restrict__ yz, float* __restrict__ dz) {
    int bm = blockIdx.x;
    int b = bm / 11, m = bm - b * 11;
    int c = threadIdx.x;
    yz[(b * 16 + m) * 128 + c] = 0.f;
    if (c == 0) dz[b * 16 + m] = 0.f;
    __shared__ float xs[128], qs[128];
    __shared__ float red[4];
    float x = query[bm * 128 + c];
    float s = x, ss = x * x;
#pragma unroll
    for (int mask = 1; mask < 64; mask <<= 1) {
        s += __shfl_xor(s, mask);
        ss += __shfl_xor(ss, mask);
    }
    int wid = threadIdx.x >> 6;
    if ((threadIdx.x & 63) == 0) { red[wid] = s; red[2 + wid] = ss; }
    __syncthreads();
    s = red[0] + red[1]; ss = red[2] + red[3];
    float mean = s * (1.f / 128.f);
    float var = ss * (1.f / 128.f) - mean * mean;
    float rstd = rsqrtf(var + 1e-5f);
    xs[c] = (x - mean) * rstd * g[c] + be[c];
    __syncthreads();
    float acc = 0.f;
#pragma unroll 8
    for (int k = 0; k < 128; k++) acc += xs[k] * Wq[k * 128 + c];
    qs[c] = acc * 0.088388347648318447f;   // 1/sqrt(128)
    __syncthreads();
    const float4* wr = (const float4*)(Wk + c * 128);   // row c of Wk
    float qk = 0.f;
#pragma unroll 8
    for (int k4 = 0; k4 < 32; k4++) {
        float4 wv = wr[k4];
        qk += qs[k4 * 4] * wv.x + qs[k4 * 4 + 1] * wv.y +
              qs[k4 * 4 + 2] * wv.z + qs[k4 * 4 + 3] * wv.w;
    }
    // A-frag packing: lane = hi*16 + m holds qk[m][kc*32 + hi*8 + j]
    int kc = c >> 5, hi = (c >> 3) & 3, j = c & 7;
    *(unsigned short*)(qfrag + b * 4096 + kc * 1024 + (hi * 16 + m) * 16 + j * 2) = f2bf(qk);
}

// ------------- kernel F: LN + materialize xln + iter-1 attention (once) -------------
// x/p double-buffered, 2 barriers/tile, DPP LN reduction.
__global__ __launch_bounds__(256) void kf(
    const float* __restrict__ inputs, const float* __restrict__ gkv,
    const float* __restrict__ bkv, const char* __restrict__ qfrag,
    char* __restrict__ kg, float* __restrict__ yacc, float* __restrict__ dacc_g) {
    __shared__ __align__(16) char smem[36864];   // x dbuf 2x16K + p dbuf 2x2K
    const int PO = 32768;
    int tid = threadIdx.x;
    int b = blockIdx.x >> 4, gt = blockIdx.x & 15;   // 4 tiles per block
    int w = tid >> 6, lane = tid & 63, hi = lane >> 4, lo = lane & 15;
    int a_ = tid >> 5, col4 = tid & 31;

    short8 qa[4];
#pragma unroll
    for (int kc = 0; kc < 4; kc++)
        qa[kc] = *(const short8*)(qfrag + b * 4096 + kc * 1024 + lane * 16);

    float4 g4  = *(const float4*)(gkv + col4 * 4);
    float4 be4 = *(const float4*)(bkv + col4 * 4);

    f32x4 y0 = {0, 0, 0, 0}, y1 = {0, 0, 0, 0};
    float dr[4] = {0, 0, 0, 0};

    const float4* inp4 = (const float4*)(inputs + ((size_t)b * NKEYS + gt * 256) * 128);

    float4 xa[8];
#pragma unroll
    for (int i = 0; i < 8; i++) xa[i] = inp4[tid + 256 * i];

#pragma unroll
    for (int t = 0; t < 4; t++) {
        int XB = (t & 1) * 16384;
        int PB = PO + (t & 1) * 2048;
        float4 xb[8];
        if (t < 3) {
#pragma unroll
            for (int i = 0; i < 8; i++) xb[i] = inp4[(t + 1) * 2048 + tid + 256 * i];
        }
        size_t tb = ((size_t)(b * 64 + gt * 4 + t)) * 16384;
        // ---- LN -> bf16: LDS (swizzled, buf t&1) + coalesced dump to kg ----
#pragma unroll
        for (int i = 0; i < 8; i++) {
            float4 xv = xa[i];
            int row = a_ + 8 * i;
            float s = xv.x + xv.y + xv.z + xv.w;
            float ss = xv.x * xv.x + xv.y * xv.y + xv.z * xv.z + xv.w * xv.w;
            // 32-lane reduce: 4 DPP steps (VALU) + 1 ds_swizzle xor16
            s = dpp_add<0xB1>(s);  ss = dpp_add<0xB1>(ss);
            s = dpp_add<0x4E>(s);  ss = dpp_add<0x4E>(ss);
            s = dpp_add<0x141>(s); ss = dpp_add<0x141>(ss);
            s = dpp_add<0x140>(s); ss = dpp_add<0x140>(ss);
            s += swz_x16(s);       ss += swz_x16(ss);
            float mean = s * (1.f / 128.f);
            float var = ss * (1.f / 128.f) - mean * mean;
            float rstd = rsqrtf(var + 1e-5f);
            unsigned short h0 = f2bf((xv.x - mean) * rstd * g4.x + be4.x);
            unsigned short h1 = f2bf((xv.y - mean) * rstd * g4.y + be4.y);
            unsigned short h2 = f2bf((xv.z - mean) * rstd * g4.z + be4.z);
            unsigned short h3 = f2bf((xv.w - mean) * rstd * g4.w + be4.w);
            uint2 pk;
            pk.x = (unsigned)h0 | ((unsigned)h1 << 16);
            pk.y = (unsigned)h2 | ((unsigned)h3 << 16);
            int off = xoff(row, col4 * 8);
            *(uint2*)(smem + XB + off) = pk;
            *(uint2*)(kg + tb + off) = pk;   // same image; wave covers full rows
        }
        asm volatile("s_waitcnt lgkmcnt(0)" ::: "memory");
        __builtin_amdgcn_s_barrier();                     // 1: x-tile visible
        __builtin_amdgcn_sched_barrier(0);

        // ---- logits (wave w: keys [16w,16w+16)) ----
        f32x4 lacc = {0, 0, 0, 0};
        int n = w * 16 + lo;
#pragma unroll
        for (int kc = 0; kc < 4; kc++) {
            short8 kf8 = *(short8*)(smem + XB + xoff(n, kc * 64 + hi * 16));
            lacc = __builtin_amdgcn_mfma_f32_16x16x32_bf16(qa[kc], kf8, lacc, 0, 0, 0);
        }
        // ---- softmax over slots ----
        float mx = -1e30f;
#pragma unroll
        for (int r = 0; r < 4; r++) {
            int m = hi * 4 + r;
            mx = fmaxf(mx, (m < 11) ? lacc[r] : -1e30f);
        }
        mx = fmaxf(mx, __shfl_xor(mx, 16));
        mx = fmaxf(mx, __shfl_xor(mx, 32));
        float p[4]; float s = 0.f;
#pragma unroll
        for (int r = 0; r < 4; r++) {
            int m = hi * 4 + r;
            p[r] = (m < 11) ? __expf(lacc[r] - mx) : 0.f;
            s += p[r];
        }
        s += __shfl_xor(s, 16);
        s += __shfl_xor(s, 32);
        float inv = 1.f / s;
#pragma unroll
        for (int r = 0; r < 4; r++) {
            p[r] *= inv;
            dr[r] += p[r];
            int m = hi * 4 + r;
            *(unsigned short*)(smem + PB + m * 128 + (((w * 16 + lo) * 2) ^ ((m & 7) << 4))) =
                f2bf(p[r]);
        }
        asm volatile("s_waitcnt lgkmcnt(0)" ::: "memory");
        __builtin_amdgcn_s_barrier();                     // 2: p visible
        __builtin_amdgcn_sched_barrier(0);

        // ---- PV: y += p @ xln (wave w owns cols [32w,32w+32)); no 3rd barrier:
        //      next tile writes the other x/p buffers, ordered by barrier 1(t+1).
#pragma unroll
        for (int s2 = 0; s2 < 2; s2++) {
            short8 pf = *(short8*)(smem + PB + lo * 128 + ((s2 * 64 + hi * 16) ^ ((lo & 7) << 4)));
            short8 v0, v1;
#pragma unroll
            for (int j = 0; j < 8; j++) {
                int nn = s2 * 32 + hi * 8 + j;
                v0[j] = *(short*)(smem + XB + xoff(nn, (w * 32 + lo) * 2));
                v1[j] = *(short*)(smem + XB + xoff(nn, (w * 32 + 16 + lo) * 2));
            }
            y0 = __builtin_amdgcn_mfma_f32_16x16x32_bf16(pf, v0, y0, 0, 0, 0);
            y1 = __builtin_amdgcn_mfma_f32_16x16x32_bf16(pf, v1, y1, 0, 0, 0);
        }
        if (t < 3) {
#pragma unroll
            for (int i = 0; i < 8; i++) xa[i] = xb[i];
        }
    }

    // ---- flush partials ----
#pragma unroll
    for (int r = 0; r < 4; r++) {
        int m = hi * 4 + r;
        if (m < 11) {
            atomicAdd(&yacc[(b * 16 + m) * 128 + w * 32 + lo], y0[r]);
            atomicAdd(&yacc[(b * 16 + m) * 128 + w * 32 + 16 + lo], y1[r]);
        }
    }
#pragma unroll
    for (int mask = 1; mask < 16; mask <<= 1) {
#pragma unroll
        for (int r = 0; r < 4; r++) dr[r] += __shfl_xor(dr[r], mask);
    }
    if (lo == 0) {
#pragma unroll
        for (int r = 0; r < 4; r++) {
            int m = hi * 4 + r;
            if (m < 11) atomicAdd(&dacc_g[b * 16 + m], dr[r]);
        }
    }
}

// ------------- kernel B: iter-2 attention from materialized xln -------------
// 2 barriers/tile; stage issued after barrier A.
__global__ __launch_bounds__(256) void kb(
    const char* __restrict__ kg, const char* __restrict__ qfrag,
    float* __restrict__ yacc, float* __restrict__ dacc_g) {
    __shared__ __align__(16) char smem[34816];   // x dbuf 2x16K + p 2K
    const int PO = 32768;
    int tid = threadIdx.x;
    int b = blockIdx.x >> 4, gt = blockIdx.x & 15;   // 4 tiles per block
    int w = tid >> 6, lane = tid & 63, hi = lane >> 4, lo = lane & 15;

    short8 qa[4];
#pragma unroll
    for (int kc = 0; kc < 4; kc++)
        qa[kc] = *(const short8*)(qfrag + b * 4096 + kc * 1024 + lane * 16);

    f32x4 y0 = {0, 0, 0, 0}, y1 = {0, 0, 0, 0};
    float dr[4] = {0, 0, 0, 0};

    size_t base = ((size_t)(b * 64 + gt * 4)) * 16384;
    int reg = w * 4096;   // per-wave staging region

    // prologue: stage tile 0 into buf0
#pragma unroll
    for (int j = 0; j < 4; j++) {
        int o = reg + j * 1024;
        gll16(kg + base + o + lane * 16, smem + o);
    }

#pragma unroll
    for (int t = 0; t < 4; t++) {
        int XB = (t & 1) * 16384;
        // tile t staged (loads issued one body ago); PV(t-1) drained per-wave
        asm volatile("s_waitcnt vmcnt(0)" ::: "memory");
        __builtin_amdgcn_s_barrier();          // A
        __builtin_amdgcn_sched_barrier(0);
        if (t < 3) {
            size_t tbn = base + (size_t)(t + 1) * 16384;
            int nb = ((t + 1) & 1) * 16384;
#pragma unroll
            for (int j = 0; j < 4; j++) {
                int o = reg + j * 1024;
                gll16(kg + tbn + o + lane * 16, smem + nb + o);
            }
        }

        // ---- logits ----
        f32x4 lacc = {0, 0, 0, 0};
        int n = w * 16 + lo;
#pragma unroll
        for (int kc = 0; kc < 4; kc++) {
            short8 kf8 = *(short8*)(smem + XB + xoff(n, kc * 64 + hi * 16));
            lacc = __builtin_amdgcn_mfma_f32_16x16x32_bf16(qa[kc], kf8, lacc, 0, 0, 0);
        }
        // ---- softmax ----
        float mx = -1e30f;
#pragma unroll
        for (int r = 0; r < 4; r++) {
            int m = hi * 4 + r;
            mx = fmaxf(mx, (m < 11) ? lacc[r] : -1e30f);
        }
        mx = fmaxf(mx, __shfl_xor(mx, 16));
        mx = fmaxf(mx, __shfl_xor(mx, 32));
        float p[4]; float s = 0.f;
#pragma unroll
        for (int r = 0; r < 4; r++) {
            int m = hi * 4 + r;
            p[r] = (m < 11) ? __expf(lacc[r] - mx) : 0.f;
            s += p[r];
        }
        s += __shfl_xor(s, 16);
        s += __shfl_xor(s, 32);
        float inv = 1.f / s;
#pragma unroll
        for (int r = 0; r < 4; r++) {
            p[r] *= inv;
            dr[r] += p[r];
            int m = hi * 4 + r;
            *(unsigned short*)(smem + PO + m * 128 + (((w * 16 + lo) * 2) ^ ((m & 7) << 4))) =
                f2bf(p[r]);
        }
        asm volatile("s_waitcnt lgkmcnt(0)" ::: "memory");
        __builtin_amdgcn_s_barrier();          // B: p visible
        __builtin_amdgcn_sched_barrier(0);

        // ---- PV ----
#pragma unroll
        for (int s2 = 0; s2 < 2; s2++) {
            short8 pf = *(short8*)(smem + PO + lo * 128 + ((s2 * 64 + hi * 16) ^ ((lo & 7) << 4)));
            short8 v0, v1;
#pragma unroll
            for (int j = 0; j < 8; j++) {
                int nn = s2 * 32 + hi * 8 + j;
                v0[j] = *(short*)(smem + XB + xoff(nn, (w * 32 + lo) * 2));
                v1[j] = *(short*)(smem + XB + xoff(nn, (w * 32 + 16 + lo) * 2));
            }
            y0 = __builtin_amdgcn_mfma_f32_16x16x32_bf16(pf, v0, y0, 0, 0, 0);
            y1 = __builtin_amdgcn_mfma_f32_16x16x32_bf16(pf, v1, y1, 0, 0, 0);
        }
        asm volatile("s_waitcnt lgkmcnt(0)" ::: "memory");   // PV reads drained
        __builtin_amdgcn_sched_barrier(0);
    }

    // ---- flush partials ----
#pragma unroll
    for (int r = 0; r < 4; r++) {
        int m = hi * 4 + r;
        if (m < 11) {
            atomicAdd(&yacc[(b * 16 + m) * 128 + w * 32 + lo], y0[r]);
            atomicAdd(&yacc[(b * 16 + m) * 128 + w * 32 + 16 + lo], y1[r]);
        }
    }
#pragma unroll
    for (int mask = 1; mask < 16; mask <<= 1) {
#pragma unroll
        for (int r = 0; r < 4; r++) dr[r] += __shfl_xor(dr[r], mask);
    }
    if (lo == 0) {
#pragma unroll
        for (int r = 0; r < 4; r++) {
            int m = hi * 4 + r;
            if (m < 11) atomicAdd(&dacc_g[b * 16 + m], dr[r]);
        }
    }
}

// ------------- kernel UN: upd=(y/(d+eps))@Wv -> GRU; mode1: + fused qq -------------
__global__ void kun(const float* __restrict__ yacc, const float* __restrict__ dacc,
                    const float* __restrict__ qcur, const float* __restrict__ Wv,
                    const float* __restrict__ W_ir, const float* __restrict__ b_ir,
                    const float* __restrict__ W_iz, const float* __restrict__ b_iz,
                    const float* __restrict__ W_hr, const float* __restrict__ W_hz,
                    const float* __restrict__ W_in, const float* __restrict__ b_in,
                    const float* __restrict__ W_hn, const float* __restrict__ b_hn,
                    float* __restrict__ qnext, int mode,
                    const float* __restrict__ lqg, const float* __restrict__ lqb,
                    const float* __restrict__ Wq, const float* __restrict__ Wk,
                    char* __restrict__ qfrag, float* __restrict__ yz,
                    float* __restrict__ dz) {
    int bm = blockIdx.x;
    int b = bm / 11, m = bm % 11;
    int c = threadIdx.x;
    __shared__ float ys[128], us[128], qs[128];
    __shared__ float red[4];
    float den = dacc[b * 16 + m] + 1e-8f;
    ys[c] = yacc[(b * 16 + m) * 128 + c] / den;
    qs[c] = qcur[bm * 128 + c];
    __syncthreads();
    float upd = 0.f;
#pragma unroll 4
    for (int k = 0; k < 128; k++) upd += ys[k] * Wv[k * 128 + c];
    us[c] = upd;
    __syncthreads();
    float air = 0, aiz = 0, ain = 0, ahr = 0, ahz = 0, ahn = 0;
#pragma unroll 4
    for (int k = 0; k < 128; k++) {
        float u = us[k], q = qs[k];
        air += u * W_ir[k * 128 + c];
        aiz += u * W_iz[k * 128 + c];
        ain += u * W_in[k * 128 + c];
        ahr += q * W_hr[k * 128 + c];
        ahz += q * W_hz[k * 128 + c];
        ahn += q * W_hn[k * 128 + c];
    }
    float r = 1.f / (1.f + expf(-(air + b_ir[c] + ahr)));
    float z = 1.f / (1.f + expf(-(aiz + b_iz[c] + ahz)));
    float n = tanhf(ain + b_in[c] + r * (ahn + b_hn[c]));
    float qn = (1.f - z) * n + z * qs[c];
    qnext[bm * 128 + c] = qn;
    if (mode == 0) return;
    // re-zero accumulators for the next iteration (own slice only)
    yz[(b * 16 + m) * 128 + c] = 0.f;
    if (c == 0) dz[b * 16 + m] = 0.f;
    // ---- fused qq: qk = (LN(qn)@Wq*scale)@Wk^T -> qfrag ----
    float s = qn, ss = qn * qn;
#pragma unroll
    for (int mask = 1; mask < 64; mask <<= 1) {
        s += __shfl_xor(s, mask);
        ss += __shfl_xor(ss, mask);
    }
    int wid = c >> 6;
    if ((c & 63) == 0) { red[wid] = s; red[2 + wid] = ss; }
    __syncthreads();
    s = red[0] + red[1]; ss = red[2] + red[3];
    float mean = s * (1.f / 128.f);
    float var = ss * (1.f / 128.f) - mean * mean;
    float rstd = rsqrtf(var + 1e-5f);
    ys[c] = (qn - mean) * rstd * lqg[c] + lqb[c];   // ys reuse: LN result
    __syncthreads();
    float acc = 0.f;
#pragma unroll 8
    for (int k = 0; k < 128; k++) acc += ys[k] * Wq[k * 128 + c];
    us[c] = acc * 0.088388347648318447f;            // us reuse: scaled q
    __syncthreads();
    const float4* wr = (const float4*)(Wk + c * 128);
    float qk = 0.f;
#pragma unroll 8
    for (int k4 = 0; k4 < 32; k4++) {
        float4 wv = wr[k4];
        qk += us[k4 * 4] * wv.x + us[k4 * 4 + 1] * wv.y +
              us[k4 * 4 + 2] * wv.z + us[k4 * 4 + 3] * wv.w;
    }
    int kc = c >> 5, hi = (c >> 3) & 3, j = c & 7;
    *(unsigned short*)(qfrag + b * 4096 + kc * 1024 + (hi * 16 + m) * 16 + j * 2) = f2bf(qk);
}

// ================= fallback path (round-1, proven) =================
__global__ void kq(const float* __restrict__ query, const float* __restrict__ g,
                   const float* __restrict__ be, const float* __restrict__ Wq,
                   float* __restrict__ qout) {
    int bm = blockIdx.x;
    int c = threadIdx.x;
    __shared__ float xs[128];
    __shared__ float red[4];
    float x = query[bm * 128 + c];
    float s = x, ss = x * x;
#pragma unroll
    for (int mask = 1; mask < 64; mask <<= 1) {
        s += __shfl_xor(s, mask);
        ss += __shfl_xor(ss, mask);
    }
    int wid = threadIdx.x >> 6;
    if ((threadIdx.x & 63) == 0) { red[wid] = s; red[2 + wid] = ss; }
    __syncthreads();
    s = red[0] + red[1]; ss = red[2] + red[3];
    float mean = s * (1.f / 128.f);
    float var = ss * (1.f / 128.f) - mean * mean;
    float rstd = rsqrtf(var + 1e-5f);
    xs[c] = (x - mean) * rstd * g[c] + be[c];
    __syncthreads();
    float acc = 0.f;
#pragma unroll 8
    for (int k = 0; k < 128; k++) acc += xs[k] * Wq[k * 128 + c];
    qout[bm * 128 + c] = acc * 0.088388347648318447f;
}

__global__ __launch_bounds__(256) void ks(
    const float* __restrict__ inputs, const float* __restrict__ gkv,
    const float* __restrict__ bkv, const float* __restrict__ Wk,
    const float* __restrict__ Wv, const float* __restrict__ qbuf,
    float* __restrict__ upd_acc, float* __restrict__ d_acc) {
    __shared__ __align__(16) char smem[51200];
    const int XO = 0, KO = 16384, VB = 32768, PO = 49152;

    int tid = threadIdx.x;
    int b = blockIdx.x >> 4, g = blockIdx.x & 15;
    int w = tid >> 6, lane = tid & 63, hi = lane >> 4, lo = lane & 15;

    short8 bk[2][4], bv[2][4];
#pragma unroll
    for (int ct = 0; ct < 2; ct++) {
        int col = w * 32 + ct * 16 + lo;
#pragma unroll
        for (int kc = 0; kc < 4; kc++) {
            short8 fk, fv;
#pragma unroll
            for (int j = 0; j < 8; j++) {
                int rr = kc * 32 + hi * 8 + j;
                fk[j] = (short)f2bf(Wk[rr * 128 + col]);
                fv[j] = (short)f2bf(Wv[rr * 128 + col]);
            }
            bk[ct][kc] = fk; bv[ct][kc] = fv;
        }
    }
    short8 qa[4];
#pragma unroll
    for (int kc = 0; kc < 4; kc++) {
        short8 f;
#pragma unroll
        for (int j = 0; j < 8; j++)
            f[j] = (lo < 11) ? (short)f2bf(qbuf[(b * 11 + lo) * 128 + kc * 32 + hi * 8 + j])
                             : (short)0;
        qa[kc] = f;
    }
    int col4 = tid & 31;
    float4 g4  = *(const float4*)(gkv + col4 * 4);
    float4 be4 = *(const float4*)(bkv + col4 * 4);

    f32x4 uacc0 = {0, 0, 0, 0}, uacc1 = {0, 0, 0, 0};
    float dacc[4] = {0, 0, 0, 0};

    const float4* inp4 = (const float4*)(inputs + ((size_t)b * NKEYS + g * 256) * 128);
    int a_ = tid >> 5;

    for (int t = 0; t < 4; t++) {
#pragma unroll
        for (int i = 0; i < 8; i++) {
            int f = tid + 256 * i;
            float4 xv = inp4[t * 2048 + f];
            int row = a_ + 8 * i;
            float s = xv.x + xv.y + xv.z + xv.w;
            float ss = xv.x * xv.x + xv.y * xv.y + xv.z * xv.z + xv.w * xv.w;
#pragma unroll
            for (int mask = 1; mask < 32; mask <<= 1) {
                s += __shfl_xor(s, mask);
                ss += __shfl_xor(ss, mask);
            }
            float mean = s * (1.f / 128.f);
            float var = ss * (1.f / 128.f) - mean * mean;
            float rstd = rsqrtf(var + 1e-5f);
            unsigned short h0 = f2bf((xv.x - mean) * rstd * g4.x + be4.x);
            unsigned short h1 = f2bf((xv.y - mean) * rstd * g4.y + be4.y);
            unsigned short h2 = f2bf((xv.z - mean) * rstd * g4.z + be4.z);
            unsigned short h3 = f2bf((xv.w - mean) * rstd * g4.w + be4.w);
            uint2 pk;
            pk.x = (unsigned)h0 | ((unsigned)h1 << 16);
            pk.y = (unsigned)h2 | ((unsigned)h3 << 16);
            int byte = row * 256 + ((col4 * 8) ^ ((row & 7) << 4));
            *(uint2*)(smem + XO + byte) = pk;
        }
        __syncthreads();
#pragma unroll
        for (int mt = 0; mt < 4; mt++) {
            f32x4 ka0 = {0,0,0,0}, ka1 = {0,0,0,0}, va0 = {0,0,0,0}, va1 = {0,0,0,0};
            int arow = mt * 16 + lo;
#pragma unroll
            for (int kc = 0; kc < 4; kc++) {
                int abyte = arow * 256 + ((kc * 64 + hi * 16) ^ ((arow & 7) << 4));
                short8 af = *(short8*)(smem + XO + abyte);
                ka0 = __builtin_amdgcn_mfma_f32_16x16x32_bf16(af, bk[0][kc], ka0, 0, 0, 0);
                ka1 = __builtin_amdgcn_mfma_f32_16x16x32_bf16(af, bk[1][kc], ka1, 0, 0, 0);
                va0 = __builtin_amdgcn_mfma_f32_16x16x32_bf16(af, bv[0][kc], va0, 0, 0, 0);
                va1 = __builtin_amdgcn_mfma_f32_16x16x32_bf16(af, bv[1][kc], va1, 0, 0, 0);
            }
#pragma unroll
            for (int r = 0; r < 4; r++) {
                int n = mt * 16 + hi * 4 + r;
                int c0 = w * 32 + lo;
                int c1 = c0 + 16;
                *(unsigned short*)(smem + KO + n * 256 + ((c0 * 2) ^ ((n & 7) << 4))) = f2bf(ka0[r]);
                *(unsigned short*)(smem + KO + n * 256 + ((c1 * 2) ^ ((n & 7) << 4))) = f2bf(ka1[r]);
                *(unsigned short*)(smem + VB + c0 * 128 + ((n * 2) ^ ((c0 & 7) << 4))) = f2bf(va0[r]);
                *(unsigned short*)(smem + VB + c1 * 128 + ((n * 2) ^ ((c1 & 7) << 4))) = f2bf(va1[r]);
            }
        }
        __syncthreads();
        {
            f32x4 lacc = {0, 0, 0, 0};
            int n = w * 16 + lo;
#pragma unroll
            for (int kc = 0; kc < 4; kc++) {
                int kbyte = n * 256 + ((kc * 64 + hi * 16) ^ ((n & 7) << 4));
                short8 kf8 = *(short8*)(smem + KO + kbyte);
                lacc = __builtin_amdgcn_mfma_f32_16x16x32_bf16(qa[kc], kf8, lacc, 0, 0, 0);
            }
            float mx = -1e30f;
#pragma unroll
            for (int r = 0; r < 4; r++) {
                int m = hi * 4 + r;
                float v = (m < 11) ? lacc[r] : -1e30f;
                mx = fmaxf(mx, v);
            }
            mx = fmaxf(mx, __shfl_xor(mx, 16));
            mx = fmaxf(mx, __shfl_xor(mx, 32));
            float p[4]; float s = 0.f;
#pragma unroll
            for (int r = 0; r < 4; r++) {
                int m = hi * 4 + r;
                p[r] = (m < 11) ? __expf(lacc[r] - mx) : 0.f;
                s += p[r];
            }
            s += __shfl_xor(s, 16);
            s += __shfl_xor(s, 32);
            float inv = 1.f / s;
#pragma unroll
            for (int r = 0; r < 4; r++) {
                p[r] *= inv;
                dacc[r] += p[r];
                int m = hi * 4 + r;
                *(unsigned short*)(smem + PO + m * 128 + (((w * 16 + lo) * 2) ^ ((m & 7) << 4))) =
                    f2bf(p[r]);
            }
        }
        __syncthreads();
#pragma unroll
        for (int kc2 = 0; kc2 < 2; kc2++) {
            int pbyte = lo * 128 + ((kc2 * 64 + hi * 16) ^ ((lo & 7) << 4));
            short8 pf = *(short8*)(smem + PO + pbyte);
            int c0 = w * 32 + lo;
            int vb0 = c0 * 128 + ((kc2 * 64 + hi * 16) ^ ((c0 & 7) << 4));
            short8 vf0 = *(short8*)(smem + VB + vb0);
            uacc0 = __builtin_amdgcn_mfma_f32_16x16x32_bf16(pf, vf0, uacc0, 0, 0, 0);
            int c1 = c0 + 16;
            int vb1 = c1 * 128 + ((kc2 * 64 + hi * 16) ^ ((c1 & 7) << 4));
            short8 vf1 = *(short8*)(smem + VB + vb1);
            uacc1 = __builtin_amdgcn_mfma_f32_16x16x32_bf16(pf, vf1, uacc1, 0, 0, 0);
        }
    }
#pragma unroll
    for (int r = 0; r < 4; r++) {
        int m = hi * 4 + r;
        if (m < 11) {
            atomicAdd(&upd_acc[(b * 16 + m) * 128 + w * 32 + lo], uacc0[r]);
            atomicAdd(&upd_acc[(b * 16 + m) * 128 + w * 32 + 16 + lo], uacc1[r]);
        }
    }
#pragma unroll
    for (int mask = 1; mask < 16; mask <<= 1) {
#pragma unroll
        for (int r = 0; r < 4; r++) dacc[r] += __shfl_xor(dacc[r], mask);
    }
    if (lo == 0) {
#pragma unroll
        for (int r = 0; r < 4; r++) {
            int m = hi * 4 + r;
            if (m < 11) atomicAdd(&d_acc[b * 16 + m], dacc[r]);
        }
    }
}

__global__ void ku(const float* __restrict__ upd_acc, const float* __restrict__ d_acc,
                   const float* __restrict__ qcur,
                   const float* __restrict__ W_ir, const float* __restrict__ b_ir,
                   const float* __restrict__ W_iz, const float* __restrict__ b_iz,
                   const float* __restrict__ W_hr, const float* __restrict__ W_hz,
                   const float* __restrict__ W_in, const float* __restrict__ b_in,
                   const float* __restrict__ W_hn, const float* __restrict__ b_hn,
                   float* __restrict__ qnext) {
    int bm = blockIdx.x;
    int b = bm / 11, m = bm % 11;
    int c = threadIdx.x;
    __shared__ float us[128], qs[128];
    float den = d_acc[b * 16 + m] + 1e-8f;
    us[c] = upd_acc[(b * 16 + m) * 128 + c] / den;
    qs[c] = qcur[bm * 128 + c];
    __syncthreads();
    float air = 0, aiz = 0, ain = 0, ahr = 0, ahz = 0, ahn = 0;
#pragma unroll 4
    for (int k = 0; k < 128; k++) {
        float u = us[k], q = qs[k];
        air += u * W_ir[k * 128 + c];
        aiz += u * W_iz[k * 128 + c];
        ain += u * W_in[k * 128 + c];
        ahr += q * W_hr[k * 128 + c];
        ahz += q * W_hz[k * 128 + c];
        ahn += q * W_hn[k * 128 + c];
    }
    float r = 1.f / (1.f + expf(-(air + b_ir[c] + ahr)));
    float z = 1.f / (1.f + expf(-(aiz + b_iz[c] + ahz)));
    float n = tanhf(ain + b_in[c] + r * (ahn + b_hn[c]));
    qnext[bm * 128 + c] = (1.f - z) * n + z * qs[c];
}

// ---------------- launch ----------------
extern "C" void kernel_launch(void* const* d_in, const int* in_sizes, int n_in,
                              void* d_out, int out_size, void* d_ws, size_t ws_size,
                              hipStream_t stream) {
    const float* query   = (const float*)d_in[0];
    const float* inputs  = (const float*)d_in[1];
    const float* ln_q_g  = (const float*)d_in[2];
    const float* ln_q_b  = (const float*)d_in[3];
    const float* ln_kv_g = (const float*)d_in[4];
    const float* ln_kv_b = (const float*)d_in[5];
    const float* Wq      = (const float*)d_in[6];
    const float* Wk      = (const float*)d_in[7];
    const float* Wv      = (const float*)d_in[8];
    const float* W_ir    = (const float*)d_in[9];
    const float* b_ir    = (const float*)d_in[10];
    const float* W_iz    = (const float*)d_in[11];
    const float* b_iz    = (const float*)d_in[12];
    const float* W_hr    = (const float*)d_in[13];
    const float* W_hz    = (const float*)d_in[14];
    const float* W_in    = (const float*)d_in[15];
    const float* b_in    = (const float*)d_in[16];
    const float* W_hn    = (const float*)d_in[17];
    const float* b_hn    = (const float*)d_in[18];

    char* ws = (char*)d_ws;
    float* query_buf = (float*)(ws);             // 64*11*128 f32 = 360448 B
    float* yacc      = (float*)(ws + 360448);    // 64*16*128 f32 = 524288 B
    float* dacc      = (float*)(ws + 884736);    // 64*16 f32     = 4096 B
    char*  qfrag     = ws + 888832;              // 64*4*64*16    = 262144 B
    char*  kg        = ws + 1150976;             // 4096 tiles * 16KB = 64 MB
    const size_t need = 1150976ull + 67108864ull;

    if (ws_size >= need) {
        // iteration 1 (kqq zeroes yacc/dacc; kf fuses LN+materialize+attn)
        kqq<<<704, 128, 0, stream>>>(query, ln_q_g, ln_q_b, Wq, Wk, qfrag, yacc, dacc);
        kf<<<1024, 256, 0, stream>>>(inputs, ln_kv_g, ln_kv_b, qfrag, kg, yacc, dacc);
        kun<<<704, 128, 0, stream>>>(yacc, dacc, query, Wv,
                                     W_ir, b_ir, W_iz, b_iz, W_hr, W_hz,
                                     W_in, b_in, W_hn, b_hn, query_buf, 1,
                                     ln_q_g, ln_q_b, Wq, Wk, qfrag, yacc, dacc);
        // iteration 2
        kb<<<1024, 256, 0, stream>>>(kg, qfrag, yacc, dacc);
        kun<<<704, 128, 0, stream>>>(yacc, dacc, query_buf, Wv,
                                     W_ir, b_ir, W_iz, b_iz, W_hr, W_hz,
                                     W_in, b_in, W_hn, b_hn, (float*)d_out, 0,
                                     ln_q_g, ln_q_b, Wq, Wk, qfrag, yacc, dacc);
    } else {
        float* q_buf = (float*)(ws + 888832);
        const float* cur = query;
        for (int it = 0; it < 2; it++) {
            kq<<<704, 128, 0, stream>>>(cur, ln_q_g, ln_q_b, Wq, q_buf);
            hipMemsetAsync(ws + 360448, 0, 524288 + 4096, stream);
            ks<<<1024, 256, 0, stream>>>(inputs, ln_kv_g, ln_kv_b, Wk, Wv, q_buf, yacc, dacc);
            float* qn = (it == 0) ? query_buf : (float*)d_out;
            ku<<<704, 128, 0, stream>>>(yacc, dacc, cur,
                                        W_ir, b_ir, W_iz, b_iz, W_hr, W_hz,
                                        W_in, b_in, W_hn, b_hn, qn);
            cur = query_buf;
        }
    }
}